// Round 18
// baseline (147.293 us; speedup 1.0000x reference)
//
#include <hip/hip_runtime.h>
#include <math.h>

#define B_   16
#define L_   4096
#define H_   512
#define P_   128
#define M_   (B_*L_)    // 65536
#define N2_  (2*P_)     // 256
#define CHK  64         // scan chunk length (for scan_chunks/scan_apply)
#define NCH  (L_/CHK)   // 64 chunks per batch

typedef __attribute__((ext_vector_type(8))) short bf16x8;
typedef __attribute__((ext_vector_type(8))) unsigned short u16x8;
typedef __attribute__((ext_vector_type(4))) float f32x4;
typedef __attribute__((ext_vector_type(4))) unsigned u32x4;

__device__ __forceinline__ unsigned short f2bf(float x) {
    unsigned u = __float_as_uint(x);
    return (unsigned short)((u + 0x7FFFu + ((u >> 16) & 1u)) >> 16);
}
__device__ __forceinline__ float bf2f(unsigned short s) {
    return __uint_as_float(((unsigned)s) << 16);
}
// packed f32x2 -> bf16x2 (RNE), single HW instr on gfx950
__device__ __forceinline__ unsigned cvtpk(float lo, float hi) {
    unsigned r;
    asm("v_cvt_pk_bf16_f32 %0, %1, %2" : "=v"(r) : "v"(lo), "v"(hi));
    return r;
}

__device__ __forceinline__ void gload16(const void* g, void* l) {
    __builtin_amdgcn_global_load_lds(
        (const __attribute__((address_space(1))) void*)g,
        (__attribute__((address_space(3))) void*)l,
        16, 0, 0);
}

// ---------------- precompute ----------------

__global__ void precompA(const float* __restrict__ lr, const float* __restrict__ li,
                         const float* __restrict__ lstep,
                         float* __restrict__ abar_r, float* __restrict__ abar_i,
                         float* __restrict__ coef_r, float* __restrict__ coef_i) {
    int p = threadIdx.x;
    if (p >= P_) return;
    double lrd = (double)lr[p], lid = (double)li[p];
    double step = exp((double)lstep[p]);       // STEP_RESCALE = 1
    double ea = exp(lrd * step);
    double abr = ea * cos(lid * step), abi = ea * sin(lid * step);
    abar_r[p] = (float)abr; abar_i[p] = (float)abi;
    double nr = abr - 1.0, ni = abi;
    double den = lrd*lrd + lid*lid;
    coef_r[p] = (float)((nr*lrd + ni*lid) / den);
    coef_i[p] = (float)((ni*lrd - nr*lid) / den);
}

// BT[n][k=h]: n<128 -> Re(coef_p * B_c[p][h]), n>=128 -> Im. bf16.
__global__ void precompBT(const float* __restrict__ Bin,
                          const float* __restrict__ coef_r, const float* __restrict__ coef_i,
                          unsigned short* __restrict__ BTh) {
    int idx = blockIdx.x * 256 + threadIdx.x;   // over 256*512
    if (idx >= N2_*H_) return;
    int n = idx >> 9, k = idx & 511;
    int p = n & (P_-1);
    float br = Bin[(p*H_ + k)*2 + 0], bi = Bin[(p*H_ + k)*2 + 1];
    float cr = coef_r[p], ci = coef_i[p];
    float v = (n < P_) ? (cr*br - ci*bi) : (cr*bi + ci*br);
    BTh[idx] = f2bf(v);
}

// CM[n=h][k]: k<128 -> 2*C_r[h][k], k>=128 -> -2*C_i[h][k-128]. bf16.
__global__ void precompCM(const float* __restrict__ Cin,
                          unsigned short* __restrict__ CMh) {
    int idx = blockIdx.x * 256 + threadIdx.x;   // over 512*256
    if (idx >= H_*N2_) return;
    int n = idx >> 8, k = idx & 255;
    float v;
    if (k < P_) v =  2.0f * Cin[(n*P_ + k)*2 + 0];
    else        v = -2.0f * Cin[(n*P_ + (k-P_))*2 + 1];
    CMh[idx] = f2bf(v);
}

// ---------------- GEMM1 + fused carry ----------------
// r16-proven GEMM: tile 128m x 256n(full-N), 512 threads = 8 waves (2m x 4n),
// BK=64, 8 K-steps, single-buffer 64KB LDS, 2-barrier loop.
// NEW: epilogue stores the bf16 bu tile into the freed 64KB LDS
// (XOR-swizzled), then 128 threads run the 128-step scan recurrence and
// emit the two chunk-64 carries directly (fuses scan_carry: -32MB, -1 launch).

template<int KSTEPS>
__global__ __launch_bounds__(512) void gemm1f(
        const float* __restrict__ A,
        const unsigned short* __restrict__ Bm,
        unsigned short* __restrict__ bu,
        const float* __restrict__ abr_, const float* __restrict__ abi_,
        float* __restrict__ carr) {
    constexpr int K = KSTEPS * 64;      // 512
    __shared__ unsigned long long smem[8192];            // 64KB
    float*          Asf = (float*)smem;                  // [128*64] f32, 32KB
    unsigned short* Bs  = (unsigned short*)(smem + 4096);// [256*64] u16, 32KB
    unsigned short* Tile= (unsigned short*)smem;         // epilogue: [128][256]

    int t = threadIdx.x;                // 0..511
    int g = blockIdx.x;
    int nid = (g & 7) * (gridDim.x >> 3) + (g >> 3);
    int m0 = nid * 128;

    int lane = t & 63;
    int w    = t >> 6;                  // 0..7
    int wr = w >> 2, wc = w & 3;        // 2m x 4n wave grid
    int lr = lane & 15, lg = lane >> 4;

    int ar_ = t >> 4;
    int asw = (t & 15) ^ (ar_ & 15);
    const float* gA = A + (size_t)(m0 + ar_) * K + asw * 4;
    int br_ = t >> 3;
    int bsw = (t & 7) ^ (br_ & 7);
    const unsigned short* gB = Bm + (size_t)br_ * K + bsw * 8;

    f32x4 acc[4][4] = {};

    for (int ks = 0; ks < KSTEPS; ++ks) {
        int k0 = ks * 64;
        __syncthreads();
#pragma unroll
        for (int i = 0; i < 4; ++i)
            gload16(gA + (size_t)(32 * i) * K + k0, &Asf[i * 2048 + w * 256]);
#pragma unroll
        for (int i = 0; i < 4; ++i)
            gload16(gB + (size_t)(64 * i) * K + k0, &Bs[i * 4096 + w * 512]);
        __syncthreads();

#pragma unroll
        for (int ku = 0; ku < 2; ++ku) {
            bf16x8 af[4], bf[4];
#pragma unroll
            for (int f = 0; f < 4; ++f) {
                int rA = wr * 64 + f * 16 + lr;             // 0..127
                int c0 = ((ku * 8 + lg * 2)     ^ rA) & 15;
                int c1 = ((ku * 8 + lg * 2 + 1) ^ rA) & 15;
                float4 a0 = *(const float4*)&Asf[rA * 64 + c0 * 4];
                float4 a1 = *(const float4*)&Asf[rA * 64 + c1 * 4];
                u32x4 q;
                q[0] = cvtpk(a0.x, a0.y);
                q[1] = cvtpk(a0.z, a0.w);
                q[2] = cvtpk(a1.x, a1.y);
                q[3] = cvtpk(a1.z, a1.w);
                af[f] = *(bf16x8*)&q;
                int rB = wc * 64 + f * 16 + lr;             // 0..255
                int cb = ((ku * 4 + lg) ^ rB) & 7;
                bf[f] = *(const bf16x8*)&Bs[rB * 64 + cb * 8];
            }
#pragma unroll
            for (int fn = 0; fn < 4; ++fn)
#pragma unroll
                for (int fm = 0; fm < 4; ++fm)
                    acc[fn][fm] = __builtin_amdgcn_mfma_f32_16x16x32_bf16(bf[fn], af[fm], acc[fn][fm], 0, 0, 0);
        }
    }

    // all waves done reading staging LDS before we overwrite it
    __syncthreads();

    // epilogue: lane lr = m, regs = 4 consecutive n.
    // Global store (unchanged) + LDS tile store, chunk-XOR-swizzled:
    // Tile[m][ (cn ^ (m&7))*8 + (n&7) ], cn = n>>3.
#pragma unroll
    for (int fn = 0; fn < 4; ++fn)
#pragma unroll
        for (int fm = 0; fm < 4; ++fm) {
            int m = wr * 64 + fm * 16 + lr;
            int n = wc * 64 + fn * 16 + lg * 4;
            unsigned o0 = cvtpk(acc[fn][fm][0], acc[fn][fm][1]);
            unsigned o1 = cvtpk(acc[fn][fm][2], acc[fn][fm][3]);
            *(uint2*)&bu[(size_t)(m0 + m) * N2_ + n] = make_uint2(o0, o1);
            int cs = ((n >> 3) ^ (m & 7));
            *(uint2*)&Tile[m * 256 + cs * 8 + (n & 7)] = make_uint2(o0, o1);
        }
    __syncthreads();

    // fused scan_carry: 128 threads, serial over 128 rows, reset at 64.
    if (t < P_) {
        int p = t;
        float ar = abr_[p], ai = abi_[p];
        int b   = m0 >> 12;            // batch
        int c64 = (m0 & (L_-1)) >> 6;  // first chunk-64 index (even)
        float xr = 0.f, xi = 0.f;
        int ch0 = p >> 3, ch1 = (p + 128) >> 3;
#pragma unroll 16
        for (int i = 0; i < 128; ++i) {
            int sw = i & 7;
            float brr = bf2f(Tile[i * 256 + ((ch0 ^ sw) << 3) + (p & 7)]);
            float bii = bf2f(Tile[i * 256 + ((ch1 ^ sw) << 3) + (p & 7)]);
            float nr = ar * xr - ai * xi + brr;
            float ni = ar * xi + ai * xr + bii;
            xr = nr; xi = ni;
            if (i == 63) {
                size_t o = ((size_t)(b * NCH + c64)) * N2_;
                carr[o + p] = xr; carr[o + p + 128] = xi;
                xr = 0.f; xi = 0.f;
            }
        }
        size_t o = ((size_t)(b * NCH + c64 + 1)) * N2_;
        carr[o + p] = xr; carr[o + p + 128] = xi;
    }
}

// ---------------- GEMM2: out = states(bf16) @ CM^T + D*Din (r16-proven) ----

template<int KSTEPS, bool HASD>
__global__ __launch_bounds__(256) void gemm_m97(
        const unsigned short* __restrict__ A,
        const unsigned short* __restrict__ Bm,
        float* __restrict__ Cout, int N,
        const float* __restrict__ Din, const float* __restrict__ Dv) {
    constexpr int K = KSTEPS * 64;      // 256
    __shared__ unsigned short As[128 * 64];  // 16KB
    __shared__ unsigned short Bs[128 * 64];  // 16KB

    int t = threadIdx.x;
    int nx = gridDim.x;
    int flat = blockIdx.x + nx * blockIdx.y;
    int per  = (nx * gridDim.y) >> 3;
    int nid  = (flat & 7) * per + (flat >> 3);
    int n0 = (nid & (nx - 1)) * 128;
    int m0 = (nid / nx) * 128;

    int lane = t & 63;
    int w    = t >> 6;
    int wr = w >> 1, wc = w & 1;
    int lr = lane & 15, lg = lane >> 4;

    int sr_ = t >> 3;
    int ssw = (t & 7) ^ (sr_ & 7);
    const unsigned short* gA = A  + (size_t)(m0 + sr_) * K + ssw * 8;
    const unsigned short* gB = Bm + (size_t)(n0 + sr_) * K + ssw * 8;

    f32x4 acc[4][4] = {};

    for (int ks = 0; ks < KSTEPS; ++ks) {
        int k0 = ks * 64;
        __syncthreads();
#pragma unroll
        for (int i = 0; i < 4; ++i) {
            gload16(gA + (size_t)(32 * i) * K + k0, &As[i * 2048 + w * 512]);
            gload16(gB + (size_t)(32 * i) * K + k0, &Bs[i * 2048 + w * 512]);
        }
        __syncthreads();

#pragma unroll
        for (int ku = 0; ku < 2; ++ku) {
            bf16x8 af[4], bf[4];
#pragma unroll
            for (int f = 0; f < 4; ++f) {
                int rA = wr * 64 + f * 16 + lr;
                int ca = ((ku * 4 + lg) ^ rA) & 7;
                af[f] = *(const bf16x8*)&As[rA * 64 + ca * 8];
                int rB = wc * 64 + f * 16 + lr;
                int cb = ((ku * 4 + lg) ^ rB) & 7;
                bf[f] = *(const bf16x8*)&Bs[rB * 64 + cb * 8];
            }
#pragma unroll
            for (int fn = 0; fn < 4; ++fn)
#pragma unroll
                for (int fm = 0; fm < 4; ++fm)
                    acc[fn][fm] = __builtin_amdgcn_mfma_f32_16x16x32_bf16(bf[fn], af[fm], acc[fn][fm], 0, 0, 0);
        }
    }

#pragma unroll
    for (int fn = 0; fn < 4; ++fn)
#pragma unroll
        for (int fm = 0; fm < 4; ++fm) {
            int m = m0 + wr * 64 + fm * 16 + lr;
            int n = n0 + wc * 64 + fn * 16 + lg * 4;
            float4 v = make_float4(acc[fn][fm][0], acc[fn][fm][1], acc[fn][fm][2], acc[fn][fm][3]);
            if (HASD) {
                float4 di = *(const float4*)&Din[(size_t)m * N + n];
                float4 dv = *(const float4*)&Dv[n];
                v.x += dv.x * di.x; v.y += dv.y * di.y;
                v.z += dv.z * di.z; v.w += dv.w * di.w;
            }
            *(float4*)&Cout[(size_t)m * N + n] = v;
        }
}

// ---------------- scan chunk-combine + apply (r17-proven) ----------------

__global__ void scan_chunks(const float* __restrict__ carr, float* __restrict__ pre,
                            const float* __restrict__ ar_, const float* __restrict__ ai_) {
    int id = blockIdx.x * 256 + threadIdx.x;
    if (id >= B_ * P_) return;
    int b = id >> 7, p = id & (P_-1);
    float mr = ar_[p], mi = ai_[p];
#pragma unroll
    for (int s = 0; s < 6; s++) { float tr = mr*mr - mi*mi; mi = 2.f*mr*mi; mr = tr; }  // a^64
    float xr = 0.f, xi = 0.f;
    for (int c = 0; c < NCH; c++) {
        size_t o = ((size_t)(b*NCH + c)) * N2_;
        pre[o + p] = xr; pre[o + p + 128] = xi;
        float cr = carr[o + p], ci = carr[o + p + 128];
        float nr = mr*xr - mi*xi + cr;
        float ni = mr*xi + mi*xr + ci;
        xr = nr; xi = ni;
    }
}

// scan_apply: bf16 bu in -> states bf16 [m][256] out
__global__ __launch_bounds__(256) void scan_apply(const unsigned short* __restrict__ bu,
        const float* __restrict__ ar_, const float* __restrict__ ai_,
        const float* __restrict__ pre, unsigned short* __restrict__ states_h) {
    __shared__ float lds[CHK][256];
    int t = threadIdx.x;
    int c = blockIdx.x, b = blockIdx.y;
    size_t base = ((size_t)(b*L_ + c*CHK)) * N2_;
    const unsigned short* g = bu + base;
#pragma unroll
    for (int it = 0; it < 8; it++) {
        int flat = it * 2048 + t * 8;
        u16x8 v = *(const u16x8*)&g[flat];
        float4 x0 = make_float4(bf2f(v[0]), bf2f(v[1]), bf2f(v[2]), bf2f(v[3]));
        float4 x1 = make_float4(bf2f(v[4]), bf2f(v[5]), bf2f(v[6]), bf2f(v[7]));
        *(float4*)&lds[0][flat]     = x0;
        *(float4*)&lds[0][flat + 4] = x1;
    }
    __syncthreads();
    if (t < 128) {
        float ar = ar_[t], ai = ai_[t];
        size_t o = ((size_t)(b*NCH + c)) * N2_;
        float xr = pre[o + t], xi = pre[o + t + 128];
        for (int i = 0; i < CHK; i++) {
            float br = lds[i][t], bi = lds[i][t + 128];
            float nr = ar*xr - ai*xi + br;
            float ni = ar*xi + ai*xr + bi;
            xr = nr; xi = ni;
            lds[i][t] = xr; lds[i][t + 128] = xi;
        }
    }
    __syncthreads();
    unsigned short* o = states_h + base;
#pragma unroll
    for (int it = 0; it < 8; it++) {
        int flat = it * 2048 + t * 8;
        float4 v0 = *(const float4*)&lds[0][flat];
        float4 v1 = *(const float4*)&lds[0][flat + 4];
        unsigned q0 = cvtpk(v0.x, v0.y);
        unsigned q1 = cvtpk(v0.z, v0.w);
        unsigned q2 = cvtpk(v1.x, v1.y);
        unsigned q3 = cvtpk(v1.z, v1.w);
        u32x4 q = {q0, q1, q2, q3};
        *(u32x4*)&o[flat] = q;
    }
}

// ---------------- launch ----------------

extern "C" void kernel_launch(void* const* d_in, const int* in_sizes, int n_in,
                              void* d_out, int out_size, void* d_ws, size_t ws_size,
                              hipStream_t stream) {
    const float* inputs = (const float*)d_in[0];
    const float* lr     = (const float*)d_in[1];
    const float* li     = (const float*)d_in[2];
    const float* Bin    = (const float*)d_in[3];
    const float* Cin    = (const float*)d_in[4];
    const float* Dv     = (const float*)d_in[5];
    const float* lstep  = (const float*)d_in[6];
    float* out = (float*)d_out;

    // d_out scratch: bu bf16 (33.5MB) at offset 0. gemm2 reads nothing from
    // d_out (Din = f32 inputs) and overwrites all of it at the end.
    unsigned short* bu = (unsigned short*)d_out;

    // d_ws (~36MB of proven 68MB)
    float* ws     = (float*)d_ws;
    float* abar_r = ws;
    float* abar_i = ws + 128;
    float* coef_r = ws + 256;
    float* coef_i = ws + 384;
    float* carr   = ws + 512;            // 16*64*256 = 262144 f32
    float* pre    = ws + 262656;         // 262144 f32
    unsigned short* BTh = (unsigned short*)(ws + 524800);   // 131072 u16
    unsigned short* CMh = BTh + N2_*H_;                     // 131072 u16
    unsigned short* states_h = CMh + H_*N2_;                // 16,777,216 u16

    hipLaunchKernelGGL(precompA, dim3(1), dim3(128), 0, stream,
                       lr, li, lstep, abar_r, abar_i, coef_r, coef_i);
    hipLaunchKernelGGL(precompBT, dim3((N2_*H_)/256), dim3(256), 0, stream,
                       Bin, coef_r, coef_i, BTh);
    hipLaunchKernelGGL(precompCM, dim3((H_*N2_)/256), dim3(256), 0, stream,
                       Cin, CMh);
    // bu = cvt(inputs) @ BT^T + fused chunk-64 carries
    hipLaunchKernelGGL((gemm1f<8>), dim3(M_/128), dim3(512), 0, stream,
                       inputs, BTh, bu, abar_r, abar_i, carr);
    hipLaunchKernelGGL(scan_chunks, dim3((B_*P_)/256), dim3(256), 0, stream,
                       carr, pre, abar_r, abar_i);
    hipLaunchKernelGGL(scan_apply, dim3(NCH, B_), dim3(256), 0, stream,
                       bu, abar_r, abar_i, pre, states_h);
    // out = states @ CM^T + D*inputs  (65536 x 256)*(256 x 512), 128x128 tiles
    hipLaunchKernelGGL((gemm_m97<4, true>), dim3(H_/128, M_/128), dim3(256), 0, stream,
                       states_h, CMh, out, H_, inputs, Dv);
}

// Round 19
// 133.595 us; speedup vs baseline: 1.1025x; 1.1025x over previous
//
#include <hip/hip_runtime.h>
#include <math.h>

#define B_   16
#define L_   4096
#define H_   512
#define P_   128
#define M_   (B_*L_)    // 65536
#define N2_  (2*P_)     // 256
#define CHK  64         // scan chunk length
#define NCH  (L_/CHK)   // 64 chunks per batch

typedef __attribute__((ext_vector_type(8))) short bf16x8;
typedef __attribute__((ext_vector_type(8))) unsigned short u16x8;
typedef __attribute__((ext_vector_type(4))) float f32x4;
typedef __attribute__((ext_vector_type(4))) unsigned u32x4;

__device__ __forceinline__ unsigned short f2bf(float x) {
    unsigned u = __float_as_uint(x);
    return (unsigned short)((u + 0x7FFFu + ((u >> 16) & 1u)) >> 16);
}
__device__ __forceinline__ float bf2f(unsigned short s) {
    return __uint_as_float(((unsigned)s) << 16);
}
// packed f32x2 -> bf16x2 (RNE), single HW instr on gfx950
__device__ __forceinline__ unsigned cvtpk(float lo, float hi) {
    unsigned r;
    asm("v_cvt_pk_bf16_f32 %0, %1, %2" : "=v"(r) : "v"(lo), "v"(hi));
    return r;
}

__device__ __forceinline__ void gload16(const void* g, void* l) {
    __builtin_amdgcn_global_load_lds(
        (const __attribute__((address_space(1))) void*)g,
        (__attribute__((address_space(3))) void*)l,
        16, 0, 0);
}

// ---------------- merged precompute ----------------
// blocks [0,512): BT; [512,1024): CM; block 1024: abar.
// Each BT thread recomputes its p's coef in double (identical formula).

__global__ void precomp_all(const float* __restrict__ lr, const float* __restrict__ li,
                            const float* __restrict__ lstep,
                            const float* __restrict__ Bin, const float* __restrict__ Cin,
                            float* __restrict__ abar_r, float* __restrict__ abar_i,
                            unsigned short* __restrict__ BTh, unsigned short* __restrict__ CMh) {
    int blk = blockIdx.x;
    int t = threadIdx.x;
    if (blk < 512) {
        int idx = blk * 256 + t;            // over 256*512
        int n = idx >> 9, k = idx & 511;
        int p = n & (P_-1);
        double lrd = (double)lr[p], lid = (double)li[p];
        double step = exp((double)lstep[p]);
        double ea = exp(lrd * step);
        double abr = ea * cos(lid * step), abi = ea * sin(lid * step);
        double nr = abr - 1.0, ni = abi;
        double den = lrd*lrd + lid*lid;
        float cr = (float)((nr*lrd + ni*lid) / den);
        float ci = (float)((ni*lrd - nr*lid) / den);
        float br = Bin[(p*H_ + k)*2 + 0], bi = Bin[(p*H_ + k)*2 + 1];
        float v = (n < P_) ? (cr*br - ci*bi) : (cr*bi + ci*br);
        BTh[idx] = f2bf(v);
    } else if (blk < 1024) {
        int idx = (blk - 512) * 256 + t;    // over 512*256
        int n = idx >> 8, k = idx & 255;
        float v;
        if (k < P_) v =  2.0f * Cin[(n*P_ + k)*2 + 0];
        else        v = -2.0f * Cin[(n*P_ + (k-P_))*2 + 1];
        CMh[idx] = f2bf(v);
    } else {
        if (t < P_) {
            int p = t;
            double lrd = (double)lr[p], lid = (double)li[p];
            double step = exp((double)lstep[p]);
            double ea = exp(lrd * step);
            abar_r[p] = (float)(ea * cos(lid * step));
            abar_i[p] = (float)(ea * sin(lid * step));
        }
    }
}

// ---------------- GEMM1: bu(bf16) = cvt(A_f32) @ BT^T (r16-proven) --------

template<int KSTEPS>
__global__ __launch_bounds__(512) void gemm1f(
        const float* __restrict__ A,
        const unsigned short* __restrict__ Bm,
        unsigned short* __restrict__ bu) {
    constexpr int K = KSTEPS * 64;      // 512
    __shared__ float Asf[128 * 64];          // 32KB
    __shared__ unsigned short Bs[256 * 64];  // 32KB

    int t = threadIdx.x;                // 0..511
    int g = blockIdx.x;
    int nid = (g & 7) * (gridDim.x >> 3) + (g >> 3);
    int m0 = nid * 128;

    int lane = t & 63;
    int w    = t >> 6;                  // 0..7
    int wr = w >> 2, wc = w & 3;        // 2m x 4n wave grid
    int lr = lane & 15, lg = lane >> 4;

    int ar_ = t >> 4;
    int asw = (t & 15) ^ (ar_ & 15);
    const float* gA = A + (size_t)(m0 + ar_) * K + asw * 4;
    int br_ = t >> 3;
    int bsw = (t & 7) ^ (br_ & 7);
    const unsigned short* gB = Bm + (size_t)br_ * K + bsw * 8;

    f32x4 acc[4][4] = {};

    for (int ks = 0; ks < KSTEPS; ++ks) {
        int k0 = ks * 64;
        __syncthreads();
#pragma unroll
        for (int i = 0; i < 4; ++i)
            gload16(gA + (size_t)(32 * i) * K + k0, &Asf[i * 2048 + w * 256]);
#pragma unroll
        for (int i = 0; i < 4; ++i)
            gload16(gB + (size_t)(64 * i) * K + k0, &Bs[i * 4096 + w * 512]);
        __syncthreads();

#pragma unroll
        for (int ku = 0; ku < 2; ++ku) {
            bf16x8 af[4], bf[4];
#pragma unroll
            for (int f = 0; f < 4; ++f) {
                int rA = wr * 64 + f * 16 + lr;             // 0..127
                int c0 = ((ku * 8 + lg * 2)     ^ rA) & 15;
                int c1 = ((ku * 8 + lg * 2 + 1) ^ rA) & 15;
                float4 a0 = *(const float4*)&Asf[rA * 64 + c0 * 4];
                float4 a1 = *(const float4*)&Asf[rA * 64 + c1 * 4];
                u32x4 q;
                q[0] = cvtpk(a0.x, a0.y);
                q[1] = cvtpk(a0.z, a0.w);
                q[2] = cvtpk(a1.x, a1.y);
                q[3] = cvtpk(a1.z, a1.w);
                af[f] = *(bf16x8*)&q;
                int rB = wc * 64 + f * 16 + lr;             // 0..255
                int cb = ((ku * 4 + lg) ^ rB) & 7;
                bf[f] = *(const bf16x8*)&Bs[rB * 64 + cb * 8];
            }
#pragma unroll
            for (int fn = 0; fn < 4; ++fn)
#pragma unroll
                for (int fm = 0; fm < 4; ++fm)
                    acc[fn][fm] = __builtin_amdgcn_mfma_f32_16x16x32_bf16(bf[fn], af[fm], acc[fn][fm], 0, 0, 0);
        }
    }

    // epilogue: lane lr = m, regs = 4 consecutive n -> uint2 bf16 stores
#pragma unroll
    for (int fn = 0; fn < 4; ++fn)
#pragma unroll
        for (int fm = 0; fm < 4; ++fm) {
            int m = m0 + wr * 64 + fm * 16 + lr;
            int n = wc * 64 + fn * 16 + lg * 4;
            unsigned o0 = cvtpk(acc[fn][fm][0], acc[fn][fm][1]);
            unsigned o1 = cvtpk(acc[fn][fm][2], acc[fn][fm][3]);
            *(uint2*)&bu[(size_t)m * N2_ + n] = make_uint2(o0, o1);
        }
}

// ---------------- GEMM2: out = states(bf16) @ CM^T + D*Din (r16-proven) ----

template<int KSTEPS, bool HASD>
__global__ __launch_bounds__(256) void gemm_m97(
        const unsigned short* __restrict__ A,
        const unsigned short* __restrict__ Bm,
        float* __restrict__ Cout, int N,
        const float* __restrict__ Din, const float* __restrict__ Dv) {
    constexpr int K = KSTEPS * 64;      // 256
    __shared__ unsigned short As[128 * 64];  // 16KB
    __shared__ unsigned short Bs[128 * 64];  // 16KB

    int t = threadIdx.x;
    int nx = gridDim.x;
    int flat = blockIdx.x + nx * blockIdx.y;
    int per  = (nx * gridDim.y) >> 3;
    int nid  = (flat & 7) * per + (flat >> 3);
    int n0 = (nid & (nx - 1)) * 128;
    int m0 = (nid / nx) * 128;

    int lane = t & 63;
    int w    = t >> 6;
    int wr = w >> 1, wc = w & 1;
    int lr = lane & 15, lg = lane >> 4;

    int sr_ = t >> 3;
    int ssw = (t & 7) ^ (sr_ & 7);
    const unsigned short* gA = A  + (size_t)(m0 + sr_) * K + ssw * 8;
    const unsigned short* gB = Bm + (size_t)(n0 + sr_) * K + ssw * 8;

    f32x4 acc[4][4] = {};

    for (int ks = 0; ks < KSTEPS; ++ks) {
        int k0 = ks * 64;
        __syncthreads();
#pragma unroll
        for (int i = 0; i < 4; ++i) {
            gload16(gA + (size_t)(32 * i) * K + k0, &As[i * 2048 + w * 512]);
            gload16(gB + (size_t)(32 * i) * K + k0, &Bs[i * 2048 + w * 512]);
        }
        __syncthreads();

#pragma unroll
        for (int ku = 0; ku < 2; ++ku) {
            bf16x8 af[4], bf[4];
#pragma unroll
            for (int f = 0; f < 4; ++f) {
                int rA = wr * 64 + f * 16 + lr;
                int ca = ((ku * 4 + lg) ^ rA) & 7;
                af[f] = *(const bf16x8*)&As[rA * 64 + ca * 8];
                int rB = wc * 64 + f * 16 + lr;
                int cb = ((ku * 4 + lg) ^ rB) & 7;
                bf[f] = *(const bf16x8*)&Bs[rB * 64 + cb * 8];
            }
#pragma unroll
            for (int fn = 0; fn < 4; ++fn)
#pragma unroll
                for (int fm = 0; fm < 4; ++fm)
                    acc[fn][fm] = __builtin_amdgcn_mfma_f32_16x16x32_bf16(bf[fn], af[fm], acc[fn][fm], 0, 0, 0);
        }
    }

#pragma unroll
    for (int fn = 0; fn < 4; ++fn)
#pragma unroll
        for (int fm = 0; fm < 4; ++fm) {
            int m = m0 + wr * 64 + fm * 16 + lr;
            int n = n0 + wc * 64 + fn * 16 + lg * 4;
            float4 v = make_float4(acc[fn][fm][0], acc[fn][fm][1], acc[fn][fm][2], acc[fn][fm][3]);
            if (HASD) {
                float4 di = *(const float4*)&Din[(size_t)m * N + n];
                float4 dv = *(const float4*)&Dv[n];
                v.x += dv.x * di.x; v.y += dv.y * di.y;
                v.z += dv.z * di.z; v.w += dv.w * di.w;
            }
            *(float4*)&Cout[(size_t)m * N + n] = v;
        }
}

// ---------------- decoupled scan over bu[b*l][256], chunk=64 ----------------

__global__ __launch_bounds__(256) void scan_carry(const unsigned short* __restrict__ bu,
        const float* __restrict__ ar_, const float* __restrict__ ai_,
        float* __restrict__ carr) {
    __shared__ float lds[CHK][256];
    int t = threadIdx.x;
    int c = blockIdx.x, b = blockIdx.y;         // c in 0..63
    size_t base = ((size_t)(b*L_ + c*CHK)) * N2_;
    const unsigned short* g = bu + base;
#pragma unroll
    for (int it = 0; it < 8; it++) {
        int flat = it * 2048 + t * 8;
        u16x8 v = *(const u16x8*)&g[flat];
        float4 x0 = make_float4(bf2f(v[0]), bf2f(v[1]), bf2f(v[2]), bf2f(v[3]));
        float4 x1 = make_float4(bf2f(v[4]), bf2f(v[5]), bf2f(v[6]), bf2f(v[7]));
        *(float4*)&lds[0][flat]     = x0;
        *(float4*)&lds[0][flat + 4] = x1;
    }
    __syncthreads();
    if (t < 128) {
        float ar = ar_[t], ai = ai_[t];
        float xr = 0.f, xi = 0.f;
        for (int i = 0; i < CHK; i++) {
            float br = lds[i][t], bi = lds[i][t + 128];
            float nr = ar*xr - ai*xi + br;
            float ni = ar*xi + ai*xr + bi;
            xr = nr; xi = ni;
        }
        size_t o = ((size_t)(b*NCH + c)) * N2_;
        carr[o + t] = xr; carr[o + t + 128] = xi;
    }
}

__global__ void scan_chunks(const float* __restrict__ carr, float* __restrict__ pre,
                            const float* __restrict__ ar_, const float* __restrict__ ai_) {
    int id = blockIdx.x * 256 + threadIdx.x;
    if (id >= B_ * P_) return;
    int b = id >> 7, p = id & (P_-1);
    float mr = ar_[p], mi = ai_[p];
#pragma unroll
    for (int s = 0; s < 6; s++) { float tr = mr*mr - mi*mi; mi = 2.f*mr*mi; mr = tr; }  // a^64
    float xr = 0.f, xi = 0.f;
    for (int c = 0; c < NCH; c++) {
        size_t o = ((size_t)(b*NCH + c)) * N2_;
        pre[o + p] = xr; pre[o + p + 128] = xi;
        float cr = carr[o + p], ci = carr[o + p + 128];
        float nr = mr*xr - mi*xi + cr;
        float ni = mr*xi + mi*xr + ci;
        xr = nr; xi = ni;
    }
}

// scan_apply: bf16 bu in -> states bf16 [m][256] out
__global__ __launch_bounds__(256) void scan_apply(const unsigned short* __restrict__ bu,
        const float* __restrict__ ar_, const float* __restrict__ ai_,
        const float* __restrict__ pre, unsigned short* __restrict__ states_h) {
    __shared__ float lds[CHK][256];
    int t = threadIdx.x;
    int c = blockIdx.x, b = blockIdx.y;
    size_t base = ((size_t)(b*L_ + c*CHK)) * N2_;
    const unsigned short* g = bu + base;
#pragma unroll
    for (int it = 0; it < 8; it++) {
        int flat = it * 2048 + t * 8;
        u16x8 v = *(const u16x8*)&g[flat];
        float4 x0 = make_float4(bf2f(v[0]), bf2f(v[1]), bf2f(v[2]), bf2f(v[3]));
        float4 x1 = make_float4(bf2f(v[4]), bf2f(v[5]), bf2f(v[6]), bf2f(v[7]));
        *(float4*)&lds[0][flat]     = x0;
        *(float4*)&lds[0][flat + 4] = x1;
    }
    __syncthreads();
    if (t < 128) {
        float ar = ar_[t], ai = ai_[t];
        size_t o = ((size_t)(b*NCH + c)) * N2_;
        float xr = pre[o + t], xi = pre[o + t + 128];
        for (int i = 0; i < CHK; i++) {
            float br = lds[i][t], bi = lds[i][t + 128];
            float nr = ar*xr - ai*xi + br;
            float ni = ar*xi + ai*xr + bi;
            xr = nr; xi = ni;
            lds[i][t] = xr; lds[i][t + 128] = xi;
        }
    }
    __syncthreads();
    unsigned short* o = states_h + base;
#pragma unroll
    for (int it = 0; it < 8; it++) {
        int flat = it * 2048 + t * 8;
        float4 v0 = *(const float4*)&lds[0][flat];
        float4 v1 = *(const float4*)&lds[0][flat + 4];
        unsigned q0 = cvtpk(v0.x, v0.y);
        unsigned q1 = cvtpk(v0.z, v0.w);
        unsigned q2 = cvtpk(v1.x, v1.y);
        unsigned q3 = cvtpk(v1.z, v1.w);
        u32x4 q = {q0, q1, q2, q3};
        *(u32x4*)&o[flat] = q;
    }
}

// ---------------- launch ----------------

extern "C" void kernel_launch(void* const* d_in, const int* in_sizes, int n_in,
                              void* d_out, int out_size, void* d_ws, size_t ws_size,
                              hipStream_t stream) {
    const float* inputs = (const float*)d_in[0];
    const float* lr     = (const float*)d_in[1];
    const float* li     = (const float*)d_in[2];
    const float* Bin    = (const float*)d_in[3];
    const float* Cin    = (const float*)d_in[4];
    const float* Dv     = (const float*)d_in[5];
    const float* lstep  = (const float*)d_in[6];
    float* out = (float*)d_out;

    // d_out scratch: bu bf16 (33.5MB) at offset 0. gemm2 reads nothing from
    // d_out (Din = f32 inputs) and overwrites all of it at the end.
    unsigned short* bu = (unsigned short*)d_out;

    // d_ws (~36MB of proven 68MB)
    float* ws     = (float*)d_ws;
    float* abar_r = ws;
    float* abar_i = ws + 128;
    float* carr   = ws + 512;            // 16*64*256 = 262144 f32
    float* pre    = ws + 262656;         // 262144 f32
    unsigned short* BTh = (unsigned short*)(ws + 524800);   // 131072 u16
    unsigned short* CMh = BTh + N2_*H_;                     // 131072 u16
    unsigned short* states_h = CMh + H_*N2_;                // 16,777,216 u16

    hipLaunchKernelGGL(precomp_all, dim3(1025), dim3(256), 0, stream,
                       lr, li, lstep, Bin, Cin, abar_r, abar_i, BTh, CMh);
    // bu = cvt(inputs) @ BT^T  (65536 x 512)*(512 x 256), 128m x full-N tiles
    hipLaunchKernelGGL((gemm1f<8>), dim3(M_/128), dim3(512), 0, stream,
                       inputs, BTh, bu);
    hipLaunchKernelGGL(scan_carry, dim3(NCH, B_), dim3(256), 0, stream,
                       bu, abar_r, abar_i, carr);
    hipLaunchKernelGGL(scan_chunks, dim3((B_*P_)/256), dim3(256), 0, stream,
                       carr, pre, abar_r, abar_i);
    hipLaunchKernelGGL(scan_apply, dim3(NCH, B_), dim3(256), 0, stream,
                       bu, abar_r, abar_i, pre, states_h);
    // out = states @ CM^T + D*inputs  (65536 x 256)*(256 x 512), 128x128 tiles
    hipLaunchKernelGGL((gemm_m97<4, true>), dim3(H_/128, M_/128), dim3(256), 0, stream,
                       states_h, CMh, out, H_, inputs, Dv);
}